// Round 1
// 401.680 us; speedup vs baseline: 1.0065x; 1.0065x over previous
//
#include <hip/hip_runtime.h>
#include <cstddef>

#define TEMP_MIN_F 1e-4f

constexpr int kS = 1024;   // frames
constexpr int kB = 256;    // batch
constexpr int kN = 256;    // channels
constexpr int kM = 512;    // z rows
constexpr int kE = 64;     // experts
constexpr int kT = kS - 1; // valid attention steps

constexpr int kChunks      = 8;              // t-chunks (grid.x)
constexpr int kChunkRows   = kS / kChunks;   // 128 rows per block
constexpr int kRowsPerWave = 32;             // own rows per wave (4 waves/block)

// workspace layout (floats)
constexpr size_t kMOff = 0;                                  // m per (b,chunk): 2048
constexpr size_t kLOff = kMOff + (size_t)kB * kChunks;       // l per (b,chunk): 2048
constexpr size_t kCOff = kLOff + (size_t)kB * kChunks;       // c0/c1: [(b*8+c)*512 + {j | 256+j}]

// ---- DPP wave reduce (gfx9 tree: shr1/2/4/8 + bcast15/31, total in lane 63) ----
template <int Ctrl, int Rmask, bool Bc>
__device__ __forceinline__ float dpp_term(float v, float old) {
  return __int_as_float(__builtin_amdgcn_update_dpp(
      __float_as_int(old), __float_as_int(v), Ctrl, Rmask, 0xf, Bc));
}

// total ends in lane 63 only (cheap form for "one lane stores" uses)
__device__ __forceinline__ float waveReduceSumL63(float v) {
  v += dpp_term<0x111, 0xf, true>(v, 0.f);   // row_shr:1
  v += dpp_term<0x112, 0xf, true>(v, 0.f);   // row_shr:2
  v += dpp_term<0x114, 0xf, true>(v, 0.f);   // row_shr:4
  v += dpp_term<0x118, 0xf, true>(v, 0.f);   // row_shr:8
  v += dpp_term<0x142, 0xa, false>(v, 0.f);  // row_bcast:15 -> rows 1,3
  v += dpp_term<0x143, 0xc, false>(v, 0.f);  // row_bcast:31 -> rows 2,3
  return v;
}

// wave-uniform result (SGPR via readlane 63)
__device__ __forceinline__ float waveReduceSum(float v) {
  v = waveReduceSumL63(v);
  return __int_as_float(__builtin_amdgcn_readlane(__float_as_int(v), 63));
}

__device__ __forceinline__ float waveReduceMax(float v) {
  v = fmaxf(v, dpp_term<0x111, 0xf, false>(v, v));
  v = fmaxf(v, dpp_term<0x112, 0xf, false>(v, v));
  v = fmaxf(v, dpp_term<0x114, 0xf, false>(v, v));
  v = fmaxf(v, dpp_term<0x118, 0xf, false>(v, v));
  v = fmaxf(v, dpp_term<0x142, 0xa, false>(v, v));
  v = fmaxf(v, dpp_term<0x143, 0xc, false>(v, v));
  return __int_as_float(__builtin_amdgcn_readlane(__float_as_int(v), 63));
}

// ---- k_fused: single pass over context with online softmax ----
// weight[t] = exp((dmin - d[t]) / T) / l  (softmax of -d/T over t).
// Wave streams rows t0..t0+lastOwn (row lastOwn = boundary, c1-only). Running
// min m only changes ~ln(32) times per stream, so the common path is a single
// __expf + plain FMAs; the rescale path has w_t == 1 exactly.
__global__ __launch_bounds__(256)
void k_fused(const float* __restrict__ context,
             const float* __restrict__ z,
             const float* __restrict__ t1p,
             float* __restrict__ ws_m,
             float* __restrict__ ws_l,
             float* __restrict__ ws_c) {
  const int c = blockIdx.x, b = blockIdx.y;
  const int tid = threadIdx.x, wave = tid >> 6, lane = tid & 63;
  const float inv_t1 = 1.0f / fmaxf(fabsf(t1p[0]), TEMP_MIN_F);

  __shared__ __align__(16) float s_z[kN]; // z[:N, b] (D = [I|0] => z_obs = z[:N])
  if (tid < kN) s_z[tid] = z[(size_t)tid * kB + b];
  __syncthreads();
  const float4 zz = ((const float4*)s_z)[lane];

  const int t0 = c * kChunkRows + wave * kRowsPerWave;
  const size_t rowStride = (size_t)kB * kN;
  const float* base = context + ((size_t)t0 * kB + b) * kN + 4 * lane;

  // rows [0, lastOwn) are own; row lastOwn is the boundary row (c1-only).
  // Every wave has exactly one boundary row (t0+lastOwn <= 1023).
  const int lastOwn = (t0 + kRowsPerWave < kS) ? kRowsPerWave : kRowsPerWave - 1;

  float m = 1e30f, l = 0.f, w_prev = 0.f;
  float4 c0 = make_float4(0.f, 0.f, 0.f, 0.f);
  float4 c1 = make_float4(0.f, 0.f, 0.f, 0.f);

  float4 xc = *(const float4*)(base);              // row 0
  float4 xn = *(const float4*)(base + rowStride);  // row 1 (always exists)
  for (int r = 0; r < lastOwn; ++r) {
    float4 x2 = xn;
    if (r + 2 <= lastOwn)  // uniform predicate
      x2 = *(const float4*)(base + (size_t)(r + 2) * rowStride);

    float pd = fabsf(xc.x - zz.x) + fabsf(xc.y - zz.y) +
               fabsf(xc.z - zz.z) + fabsf(xc.w - zz.w);
    const float d = waveReduceSum(pd);  // wave-uniform (SGPR)

    if (__builtin_expect(d < m, 0)) {
      // new running min: rescale; w_t = exp((d-d)/T) = 1
      const float alpha = __expf((d - m) * inv_t1);  // first iter: exp(-huge)=0
      const float wp = w_prev * alpha;
      l = fmaf(l, alpha, 1.f);
      c0.x = fmaf(c0.x, alpha, xc.x); c0.y = fmaf(c0.y, alpha, xc.y);
      c0.z = fmaf(c0.z, alpha, xc.z); c0.w = fmaf(c0.w, alpha, xc.w);
      c1.x = fmaf(c1.x, alpha, wp * xc.x); c1.y = fmaf(c1.y, alpha, wp * xc.y);
      c1.z = fmaf(c1.z, alpha, wp * xc.z); c1.w = fmaf(c1.w, alpha, wp * xc.w);
      w_prev = 1.f;
      m = d;
    } else {
      const float w = __expf((m - d) * inv_t1);
      l += w;
      c0.x = fmaf(w, xc.x, c0.x); c0.y = fmaf(w, xc.y, c0.y);
      c0.z = fmaf(w, xc.z, c0.z); c0.w = fmaf(w, xc.w, c0.w);
      c1.x = fmaf(w_prev, xc.x, c1.x); c1.y = fmaf(w_prev, xc.y, c1.y);
      c1.z = fmaf(w_prev, xc.z, c1.z); c1.w = fmaf(w_prev, xc.w, c1.w);
      w_prev = w;
    }
    xc = xn; xn = x2;
  }
  // boundary row: contributes only w[t-1]*x[t] to c1
  c1.x = fmaf(w_prev, xc.x, c1.x); c1.y = fmaf(w_prev, xc.y, c1.y);
  c1.z = fmaf(w_prev, xc.z, c1.z); c1.w = fmaf(w_prev, xc.w, c1.w);

  // ---- merge the block's 4 waves (flash-style) ----
  __shared__ float s_m[4], s_l[4];
  __shared__ __align__(16) float s_cc[4][2 * kN]; // 8 KB
  if (lane == 0) s_m[wave] = m;
  __syncthreads();
  const float m_blk = fminf(fminf(s_m[0], s_m[1]), fminf(s_m[2], s_m[3]));
  const float aw = __expf((m_blk - m) * inv_t1);
  if (lane == 0) s_l[wave] = l * aw;
  ((float4*)&s_cc[wave][0])[lane] =
      make_float4(c0.x * aw, c0.y * aw, c0.z * aw, c0.w * aw);
  ((float4*)&s_cc[wave][kN])[lane] =
      make_float4(c1.x * aw, c1.y * aw, c1.z * aw, c1.w * aw);
  __syncthreads();

  const size_t pc = (size_t)b * kChunks + c;
  if (tid < kN) {
    float p0 = s_cc[0][tid] + s_cc[1][tid] + s_cc[2][tid] + s_cc[3][tid];
    float p1 = s_cc[0][kN + tid] + s_cc[1][kN + tid] +
               s_cc[2][kN + tid] + s_cc[3][kN + tid];
    ws_c[pc * (2 * kN) + tid] = p0;
    ws_c[pc * (2 * kN) + kN + tid] = p1;
  }
  if (tid == 0) {
    ws_m[pc] = m_blk;
    ws_l[pc] = s_l[0] + s_l[1] + s_l[2] + s_l[3];
  }
}

// ---- k_tail: flash-merge 8 chunks + conv-collapse GEMV + MLP + softmax ----
__global__ __launch_bounds__(512)
void k_tail(const float* __restrict__ ws_m,
            const float* __restrict__ ws_l,
            const float* __restrict__ ws_c,
            const float* __restrict__ z,
            const float* __restrict__ conv_w,
            const float* __restrict__ conv_b,
            const float* __restrict__ W1,
            const float* __restrict__ W2,
            const float* __restrict__ t1p,
            const float* __restrict__ t2p,
            float* __restrict__ out) {
  const int b = blockIdx.x;
  const int tid = threadIdx.x, wave = tid >> 6, lane = tid & 63;
  const float inv_t1 = 1.0f / fmaxf(fabsf(t1p[0]), TEMP_MIN_F);

  __shared__ __align__(16) float s_z[kM];
  __shared__ __align__(16) float s_c[2][kN];
  __shared__ __align__(16) float s_emb[kN];
  __shared__ float s_h[kE];
  __shared__ float s_mt[kChunks], s_lt[kChunks], s_alpha[kChunks];
  __shared__ float s_invl;

  for (int mm = tid; mm < kM; mm += 512) s_z[mm] = z[(size_t)mm * kB + b];
  if (tid < kChunks) {
    s_mt[tid] = ws_m[(size_t)b * kChunks + tid];
    s_lt[tid] = ws_l[(size_t)b * kChunks + tid];
  }
  __syncthreads();
  if (tid < kChunks) {
    float mg = s_mt[0];
#pragma unroll
    for (int cc = 1; cc < kChunks; ++cc) mg = fminf(mg, s_mt[cc]);
    s_alpha[tid] = __expf((mg - s_mt[tid]) * inv_t1);
  }
  __syncthreads();
  if (tid == 0) {
    float lt = 0.f;
#pragma unroll
    for (int cc = 0; cc < kChunks; ++cc) lt += s_alpha[cc] * s_lt[cc];
    s_invl = 1.0f / lt;
  }
  __syncthreads();
  if (tid < kN) {
    float p0 = 0.f, p1 = 0.f;
#pragma unroll
    for (int cc = 0; cc < kChunks; ++cc) {
      const size_t o = ((size_t)b * kChunks + cc) * (2 * kN);
      p0 += s_alpha[cc] * ws_c[o + tid];
      p1 += s_alpha[cc] * ws_c[o + kN + tid];
    }
    s_c[0][tid] = p0 * s_invl;
    s_c[1][tid] = p1 * s_invl;
  }
  __syncthreads();

  // embedding[o] = conv_w[o,:,0].c0 + conv_w[o,:,1].c1 + conv_b[o]
  const float4 cc0 = ((const float4*)&s_c[0][0])[lane];
  const float4 cc1 = ((const float4*)&s_c[1][0])[lane];
#pragma unroll 4
  for (int o = wave; o < kN; o += 8) {
    const float4* wrow = (const float4*)(conv_w + (size_t)o * (2 * kN));
    float4 wa = wrow[2 * lane];       // (i=4l,k=0),(4l,1),(4l+1,0),(4l+1,1)
    float4 wb = wrow[2 * lane + 1];   // (4l+2,0),(4l+2,1),(4l+3,0),(4l+3,1)
    float acc = wa.x * cc0.x + wa.y * cc1.x + wa.z * cc0.y + wa.w * cc1.y +
                wb.x * cc0.z + wb.y * cc1.z + wb.z * cc0.w + wb.w * cc1.w;
    acc = waveReduceSumL63(acc);
    if (lane == 63) s_emb[o] = acc + conv_b[o];
  }
  __syncthreads();

  // h[e] = relu([emb; z] . W1[e,:])
  for (int e = wave; e < kE; e += 8) {
    const float* wr = W1 + (size_t)e * (kN + kM);
    float acc = 0.f;
#pragma unroll
    for (int jj = 0; jj < 12; ++jj) {
      int j = lane + 64 * jj;
      float cj = (j < kN) ? s_emb[j] : s_z[j - kN];
      acc += wr[j] * cj;
    }
    acc = waveReduceSumL63(acc);
    if (lane == 63) s_h[e] = fmaxf(acc, 0.f);
  }
  __syncthreads();

  // mlp + softmax over experts (wave 0, lane = expert)
  if (wave == 0) {
    const float temp2 = fmaxf(fabsf(t2p[0]), TEMP_MIN_F);
    float acc = 0.f;
    const float* w2r = W2 + (size_t)lane * kE;
#pragma unroll
    for (int e = 0; e < kE; ++e) acc += w2r[e] * s_h[e];
    float logit = -acc / temp2;
    float mx = waveReduceMax(logit);
    float ex = __expf(logit - mx);
    float ssum = waveReduceSum(ex);
    out[(size_t)lane * kB + b] = ex / ssum;
  }
}

extern "C" void kernel_launch(void* const* d_in, const int* in_sizes, int n_in,
                              void* d_out, int out_size, void* d_ws, size_t ws_size,
                              hipStream_t stream) {
  const float* context = (const float*)d_in[0];
  const float* z       = (const float*)d_in[1];
  // d_in[2] = D — structurally [I_N | 0]; D@z == z[:N,:], so unused.
  const float* conv_w  = (const float*)d_in[3];
  const float* conv_b  = (const float*)d_in[4];
  const float* W1      = (const float*)d_in[5];
  const float* W2      = (const float*)d_in[6];
  const float* t1      = (const float*)d_in[7];
  const float* t2      = (const float*)d_in[8];
  float* out = (float*)d_out;

  float* ws   = (float*)d_ws;
  float* ws_m = ws + kMOff;
  float* ws_l = ws + kLOff;
  float* ws_c = ws + kCOff;

  hipLaunchKernelGGL(k_fused, dim3(kChunks, kB), dim3(256), 0, stream,
                     context, z, t1, ws_m, ws_l, ws_c);
  hipLaunchKernelGGL(k_tail, dim3(kB), dim3(512), 0, stream,
                     ws_m, ws_l, ws_c, z, conv_w, conv_b, W1, W2, t1, t2, out);
}

// Round 2
// 383.547 us; speedup vs baseline: 1.0541x; 1.0473x over previous
//
#include <hip/hip_runtime.h>
#include <cstddef>

#define TEMP_MIN_F 1e-4f

constexpr int kS = 1024;   // frames
constexpr int kB = 256;    // batch
constexpr int kN = 256;    // channels
constexpr int kM = 512;    // z rows
constexpr int kE = 64;     // experts
constexpr int kT = kS - 1; // valid attention steps

constexpr int kWaves       = 16;            // waves per block (1024 threads)
constexpr int kRowsPerWave = kS / kWaves;   // 64 own rows per wave

// ---- DPP wave reduce (gfx9 tree: shr1/2/4/8 + bcast15/31, total in lane 63) ----
template <int Ctrl, int Rmask, bool Bc>
__device__ __forceinline__ float dpp_term(float v, float old) {
  return __int_as_float(__builtin_amdgcn_update_dpp(
      __float_as_int(old), __float_as_int(v), Ctrl, Rmask, 0xf, Bc));
}

// total ends in lane 63 only (cheap form for "one lane stores" uses)
__device__ __forceinline__ float waveReduceSumL63(float v) {
  v += dpp_term<0x111, 0xf, true>(v, 0.f);   // row_shr:1
  v += dpp_term<0x112, 0xf, true>(v, 0.f);   // row_shr:2
  v += dpp_term<0x114, 0xf, true>(v, 0.f);   // row_shr:4
  v += dpp_term<0x118, 0xf, true>(v, 0.f);   // row_shr:8
  v += dpp_term<0x142, 0xa, false>(v, 0.f);  // row_bcast:15 -> rows 1,3
  v += dpp_term<0x143, 0xc, false>(v, 0.f);  // row_bcast:31 -> rows 2,3
  return v;
}

// wave-uniform result (SGPR via readlane 63)
__device__ __forceinline__ float waveReduceSum(float v) {
  v = waveReduceSumL63(v);
  return __int_as_float(__builtin_amdgcn_readlane(__float_as_int(v), 63));
}

__device__ __forceinline__ float waveReduceMax(float v) {
  v = fmaxf(v, dpp_term<0x111, 0xf, false>(v, v));
  v = fmaxf(v, dpp_term<0x112, 0xf, false>(v, v));
  v = fmaxf(v, dpp_term<0x114, 0xf, false>(v, v));
  v = fmaxf(v, dpp_term<0x118, 0xf, false>(v, v));
  v = fmaxf(v, dpp_term<0x142, 0xa, false>(v, v));
  v = fmaxf(v, dpp_term<0x143, 0xc, false>(v, v));
  return __int_as_float(__builtin_amdgcn_readlane(__float_as_int(v), 63));
}

// ---- k_all: fully fused. One block per batch b; 16 waves stream 64 rows
// each with the online-softmax recurrence (weight[t] = exp((dmin-d[t])/T)/l):
//   c0 = sum_t w[t] x[t],  c1 = sum_t w[t] x[t+1]
// then 16-way flash-merge in LDS, conv-collapse GEMV, MLP, expert softmax.
// No workspace, no second launch.
__global__ __launch_bounds__(1024)
void k_all(const float* __restrict__ context,
           const float* __restrict__ z,
           const float* __restrict__ conv_w,
           const float* __restrict__ conv_b,
           const float* __restrict__ W1,
           const float* __restrict__ W2,
           const float* __restrict__ t1p,
           const float* __restrict__ t2p,
           float* __restrict__ out) {
  const int b = blockIdx.x;
  const int tid = threadIdx.x, wave = tid >> 6, lane = tid & 63;
  const float inv_t1 = 1.0f / fmaxf(fabsf(t1p[0]), TEMP_MIN_F);

  __shared__ __align__(16) float s_z[kM];               // z[:, b] (2 KB)
  __shared__ __align__(16) float s_cc[kWaves][2 * kN];  // 32 KB wave partials
  __shared__ float s_m[kWaves], s_l[kWaves];
  __shared__ __align__(16) float s_c0[kN];
  __shared__ __align__(16) float s_c1[kN];
  __shared__ __align__(16) float s_emb[kN];
  __shared__ float s_h[kE];
  __shared__ float s_invl;

  for (int mm = tid; mm < kM; mm += 1024) s_z[mm] = z[(size_t)mm * kB + b];
  __syncthreads();
  // D = [I_N | 0] => z_obs = z[:N, b]; each lane holds 4 channels
  const float4 zz = ((const float4*)s_z)[lane];

  const int t0 = wave * kRowsPerWave;
  const size_t rowStride = (size_t)kB * kN;
  const float* base = context + ((size_t)t0 * kB + b) * kN + 4 * lane;

  // rows [0,lastOwn) own; row lastOwn = boundary (c1-only). Wave 15: t=1023
  // is not a valid attention step, so its own range shrinks by one.
  const int lastOwn = (t0 + kRowsPerWave < kS) ? kRowsPerWave : kRowsPerWave - 1;

  float m = 1e30f, l = 0.f, w_prev = 0.f;
  float4 c0 = make_float4(0.f, 0.f, 0.f, 0.f);
  float4 c1 = make_float4(0.f, 0.f, 0.f, 0.f);

  float4 xc = *(const float4*)(base);              // row 0
  float4 xn = *(const float4*)(base + rowStride);  // row 1 (always exists)
  for (int r = 0; r < lastOwn; ++r) {
    float4 x2 = xn;
    if (r + 2 <= lastOwn)  // uniform predicate, never OOB
      x2 = *(const float4*)(base + (size_t)(r + 2) * rowStride);

    float pd = fabsf(xc.x - zz.x) + fabsf(xc.y - zz.y) +
               fabsf(xc.z - zz.z) + fabsf(xc.w - zz.w);
    const float d = waveReduceSum(pd);  // wave-uniform (SGPR)

    if (__builtin_expect(d < m, 0)) {
      // new running min: rescale; w_t = exp(0) = 1
      const float alpha = __expf((d - m) * inv_t1);  // first iter: exp(-huge)=0
      const float wp = w_prev * alpha;
      l = fmaf(l, alpha, 1.f);
      c0.x = fmaf(c0.x, alpha, xc.x); c0.y = fmaf(c0.y, alpha, xc.y);
      c0.z = fmaf(c0.z, alpha, xc.z); c0.w = fmaf(c0.w, alpha, xc.w);
      c1.x = fmaf(c1.x, alpha, wp * xc.x); c1.y = fmaf(c1.y, alpha, wp * xc.y);
      c1.z = fmaf(c1.z, alpha, wp * xc.z); c1.w = fmaf(c1.w, alpha, wp * xc.w);
      w_prev = 1.f;
      m = d;
    } else {
      const float w = __expf((m - d) * inv_t1);
      l += w;
      c0.x = fmaf(w, xc.x, c0.x); c0.y = fmaf(w, xc.y, c0.y);
      c0.z = fmaf(w, xc.z, c0.z); c0.w = fmaf(w, xc.w, c0.w);
      c1.x = fmaf(w_prev, xc.x, c1.x); c1.y = fmaf(w_prev, xc.y, c1.y);
      c1.z = fmaf(w_prev, xc.z, c1.z); c1.w = fmaf(w_prev, xc.w, c1.w);
      w_prev = w;
    }
    xc = xn; xn = x2;
  }
  // boundary row: contributes only w[t-1]*x[t] to c1
  c1.x = fmaf(w_prev, xc.x, c1.x); c1.y = fmaf(w_prev, xc.y, c1.y);
  c1.z = fmaf(w_prev, xc.z, c1.z); c1.w = fmaf(w_prev, xc.w, c1.w);

  // ---- merge the block's 16 waves (flash-style) ----
  if (lane == 0) s_m[wave] = m;
  __syncthreads();
  float m_blk = s_m[0];
#pragma unroll
  for (int i = 1; i < kWaves; ++i) m_blk = fminf(m_blk, s_m[i]);
  const float aw = __expf((m_blk - m) * inv_t1);
  if (lane == 0) s_l[wave] = l * aw;
  ((float4*)&s_cc[wave][0])[lane] =
      make_float4(c0.x * aw, c0.y * aw, c0.z * aw, c0.w * aw);
  ((float4*)&s_cc[wave][kN])[lane] =
      make_float4(c1.x * aw, c1.y * aw, c1.z * aw, c1.w * aw);
  __syncthreads();

  // sum 16 partials; normalize by total l
  const int j = tid & 255, sel = (tid >> 8) & 1;
  float p = 0.f;
  if (tid < 512) {
#pragma unroll
    for (int w = 0; w < kWaves; ++w) p += s_cc[w][sel * kN + j];
  }
  if (tid == 0) {
    float lt = 0.f;
#pragma unroll
    for (int i = 0; i < kWaves; ++i) lt += s_l[i];
    s_invl = 1.0f / lt;
  }
  __syncthreads();
  if (tid < 512) (sel ? s_c1 : s_c0)[j] = p * s_invl;
  __syncthreads();

  // embedding[o] = conv_w[o,:,0].c0 + conv_w[o,:,1].c1 + conv_b[o]
  const float4 cc0 = ((const float4*)s_c0)[lane];
  const float4 cc1 = ((const float4*)s_c1)[lane];
#pragma unroll 4
  for (int o = wave; o < kN; o += kWaves) {
    const float4* wrow = (const float4*)(conv_w + (size_t)o * (2 * kN));
    float4 wa = wrow[2 * lane];       // (i=4l,k=0),(4l,1),(4l+1,0),(4l+1,1)
    float4 wb = wrow[2 * lane + 1];   // (4l+2,0),(4l+2,1),(4l+3,0),(4l+3,1)
    float acc = wa.x * cc0.x + wa.y * cc1.x + wa.z * cc0.y + wa.w * cc1.y +
                wb.x * cc0.z + wb.y * cc1.z + wb.z * cc0.w + wb.w * cc1.w;
    acc = waveReduceSumL63(acc);
    if (lane == 63) s_emb[o] = acc + conv_b[o];
  }
  __syncthreads();

  // h[e] = relu([emb; z] . W1[e,:])
  for (int e = wave; e < kE; e += kWaves) {
    const float* wr = W1 + (size_t)e * (kN + kM);
    float acc = 0.f;
#pragma unroll
    for (int jj = 0; jj < 12; ++jj) {
      int jx = lane + 64 * jj;
      float cj = (jx < kN) ? s_emb[jx] : s_z[jx - kN];
      acc += wr[jx] * cj;
    }
    acc = waveReduceSumL63(acc);
    if (lane == 63) s_h[e] = fmaxf(acc, 0.f);
  }
  __syncthreads();

  // mlp + softmax over experts (wave 0, lane = expert)
  if (wave == 0) {
    const float temp2 = fmaxf(fabsf(t2p[0]), TEMP_MIN_F);
    float acc = 0.f;
    const float* w2r = W2 + (size_t)lane * kE;
#pragma unroll
    for (int e = 0; e < kE; ++e) acc += w2r[e] * s_h[e];
    float logit = -acc / temp2;
    float mx = waveReduceMax(logit);
    float ex = __expf(logit - mx);
    float ssum = waveReduceSum(ex);
    out[(size_t)lane * kB + b] = ex / ssum;
  }
}

extern "C" void kernel_launch(void* const* d_in, const int* in_sizes, int n_in,
                              void* d_out, int out_size, void* d_ws, size_t ws_size,
                              hipStream_t stream) {
  const float* context = (const float*)d_in[0];
  const float* z       = (const float*)d_in[1];
  // d_in[2] = D — structurally [I_N | 0]; D@z == z[:N,:], so unused.
  const float* conv_w  = (const float*)d_in[3];
  const float* conv_b  = (const float*)d_in[4];
  const float* W1      = (const float*)d_in[5];
  const float* W2      = (const float*)d_in[6];
  const float* t1      = (const float*)d_in[7];
  const float* t2      = (const float*)d_in[8];
  float* out = (float*)d_out;
  (void)d_ws; (void)ws_size;  // fully fused: no workspace round-trip

  hipLaunchKernelGGL(k_all, dim3(kB), dim3(1024), 0, stream,
                     context, z, conv_w, conv_b, W1, W2, t1, t2, out);
}

// Round 4
// 363.040 us; speedup vs baseline: 1.1137x; 1.0565x over previous
//
#include <hip/hip_runtime.h>
#include <cstddef>

#define TEMP_MIN_F 1e-4f

constexpr int kS = 1024;   // frames
constexpr int kB = 256;    // batch
constexpr int kN = 256;    // channels
constexpr int kM = 512;    // z rows
constexpr int kE = 64;     // experts
constexpr int kT = kS - 1; // valid attention steps

constexpr int kWaves       = 16;            // waves per block (1024 threads)
constexpr int kRowsPerWave = kS / kWaves;   // 64 own rows per wave

typedef float v4 __attribute__((ext_vector_type(4)));

// ---- DPP wave reduce (gfx9 tree: shr1/2/4/8 + bcast15/31, total in lane 63) ----
template <int Ctrl, int Rmask, bool Bc>
__device__ __forceinline__ float dpp_term(float v, float old) {
  return __int_as_float(__builtin_amdgcn_update_dpp(
      __float_as_int(old), __float_as_int(v), Ctrl, Rmask, 0xf, Bc));
}

// total ends in lane 63 only (cheap form for "one lane stores" uses)
__device__ __forceinline__ float waveReduceSumL63(float v) {
  v += dpp_term<0x111, 0xf, true>(v, 0.f);   // row_shr:1
  v += dpp_term<0x112, 0xf, true>(v, 0.f);   // row_shr:2
  v += dpp_term<0x114, 0xf, true>(v, 0.f);   // row_shr:4
  v += dpp_term<0x118, 0xf, true>(v, 0.f);   // row_shr:8
  v += dpp_term<0x142, 0xa, false>(v, 0.f);  // row_bcast:15 -> rows 1,3
  v += dpp_term<0x143, 0xc, false>(v, 0.f);  // row_bcast:31 -> rows 2,3
  return v;
}

// wave-uniform result (SGPR via readlane 63)
__device__ __forceinline__ float waveReduceSum(float v) {
  v = waveReduceSumL63(v);
  return __int_as_float(__builtin_amdgcn_readlane(__float_as_int(v), 63));
}

__device__ __forceinline__ float waveReduceMax(float v) {
  v = fmaxf(v, dpp_term<0x111, 0xf, false>(v, v));
  v = fmaxf(v, dpp_term<0x112, 0xf, false>(v, v));
  v = fmaxf(v, dpp_term<0x114, 0xf, false>(v, v));
  v = fmaxf(v, dpp_term<0x118, 0xf, false>(v, v));
  v = fmaxf(v, dpp_term<0x142, 0xa, false>(v, v));
  v = fmaxf(v, dpp_term<0x143, 0xc, false>(v, v));
  return __int_as_float(__builtin_amdgcn_readlane(__float_as_int(v), 63));
}

// ---- k_all: fully fused. One block per batch b; 16 waves stream 64 rows
// each with the online-softmax recurrence (weight[t] = exp((dmin-d[t])/T)/l):
//   c0 = sum_t w[t] x[t],  c1 = sum_t w[t] x[t+1]
// then 16-way flash-merge in LDS, conv-collapse GEMV, MLP, expert softmax.
// Stream uses NON-TEMPORAL loads (no L2 retention needed; keeps weights
// resident); weights bulk-prewarmed into L2 right after the stream loop.
__global__ __launch_bounds__(1024)
void k_all(const float* __restrict__ context,
           const float* __restrict__ z,
           const float* __restrict__ conv_w,
           const float* __restrict__ conv_b,
           const float* __restrict__ W1,
           const float* __restrict__ W2,
           const float* __restrict__ t1p,
           const float* __restrict__ t2p,
           float* __restrict__ out) {
  const int b = blockIdx.x;
  const int tid = threadIdx.x, wave = tid >> 6, lane = tid & 63;
  const float inv_t1 = 1.0f / fmaxf(fabsf(t1p[0]), TEMP_MIN_F);

  __shared__ __align__(16) float s_z[kM];               // z[:, b] (2 KB)
  __shared__ __align__(16) float s_cc[kWaves][2 * kN];  // 32 KB wave partials
  __shared__ float s_m[kWaves], s_l[kWaves];
  __shared__ __align__(16) float s_c0[kN];
  __shared__ __align__(16) float s_c1[kN];
  __shared__ __align__(16) float s_emb[kN];
  __shared__ float s_h[kE];
  __shared__ float s_invl;

  for (int mm = tid; mm < kM; mm += 1024) s_z[mm] = z[(size_t)mm * kB + b];
  __syncthreads();
  // D = [I_N | 0] => z_obs = z[:N, b]; each lane holds 4 channels
  const v4 zz = ((const v4*)s_z)[lane];

  const int t0 = wave * kRowsPerWave;
  const size_t rowStride = (size_t)kB * kN;
  const float* base = context + ((size_t)t0 * kB + b) * kN + 4 * lane;

  // rows [0,lastOwn) own; row lastOwn = boundary (c1-only). Wave 15: t=1023
  // is not a valid attention step, so its own range shrinks by one.
  const int lastOwn = (t0 + kRowsPerWave < kS) ? kRowsPerWave : kRowsPerWave - 1;

  float m = 1e30f, l = 0.f, w_prev = 0.f;
  v4 c0 = {0.f, 0.f, 0.f, 0.f};
  v4 c1 = {0.f, 0.f, 0.f, 0.f};

  // 3-deep non-temporal prefetch (rows 0,1,2 always exist: lastOwn >= 63)
  v4 q0 = __builtin_nontemporal_load((const v4*)(base));
  v4 q1 = __builtin_nontemporal_load((const v4*)(base + rowStride));
  v4 q2 = __builtin_nontemporal_load((const v4*)(base + 2 * rowStride));
  for (int r = 0; r < lastOwn; ++r) {
    v4 q3 = q2;
    if (r + 3 <= lastOwn)  // uniform predicate, never OOB
      q3 = __builtin_nontemporal_load(
          (const v4*)(base + (size_t)(r + 3) * rowStride));

    float pd = fabsf(q0[0] - zz[0]) + fabsf(q0[1] - zz[1]) +
               fabsf(q0[2] - zz[2]) + fabsf(q0[3] - zz[3]);
    const float d = waveReduceSum(pd);  // wave-uniform (SGPR)

    if (__builtin_expect(d < m, 0)) {
      // new running min: rescale; w_t = exp(0) = 1
      const float alpha = __expf((d - m) * inv_t1);  // first iter: exp(-huge)=0
      const float wp = w_prev * alpha;
      l = fmaf(l, alpha, 1.f);
      c0[0] = fmaf(c0[0], alpha, q0[0]); c0[1] = fmaf(c0[1], alpha, q0[1]);
      c0[2] = fmaf(c0[2], alpha, q0[2]); c0[3] = fmaf(c0[3], alpha, q0[3]);
      c1[0] = fmaf(c1[0], alpha, wp * q0[0]); c1[1] = fmaf(c1[1], alpha, wp * q0[1]);
      c1[2] = fmaf(c1[2], alpha, wp * q0[2]); c1[3] = fmaf(c1[3], alpha, wp * q0[3]);
      w_prev = 1.f;
      m = d;
    } else {
      const float w = __expf((m - d) * inv_t1);
      l += w;
      c0[0] = fmaf(w, q0[0], c0[0]); c0[1] = fmaf(w, q0[1], c0[1]);
      c0[2] = fmaf(w, q0[2], c0[2]); c0[3] = fmaf(w, q0[3], c0[3]);
      c1[0] = fmaf(w_prev, q0[0], c1[0]); c1[1] = fmaf(w_prev, q0[1], c1[1]);
      c1[2] = fmaf(w_prev, q0[2], c1[2]); c1[3] = fmaf(w_prev, q0[3], c1[3]);
      w_prev = w;
    }
    q0 = q1; q1 = q2; q2 = q3;
  }
  // boundary row: contributes only w[t-1]*x[t] to c1
  c1[0] = fmaf(w_prev, q0[0], c1[0]); c1[1] = fmaf(w_prev, q0[1], c1[1]);
  c1[2] = fmaf(w_prev, q0[2], c1[2]); c1[3] = fmaf(w_prev, q0[3], c1[3]);

  // ---- bulk weight prewarm into L2 (NORMAL loads, retained) ----
  // 32 blocks per XCD (b%8 = XCD); slice b>>3 gives each a distinct 1/32
  // of the weights => full coverage per XCD. Issued here so the merge
  // barrier's vmcnt drain absorbs the latency in one parallel burst.
  // Bounds: slice<=31 -> conv_w max idx 31*1024+1023 = 32767 (< 256*512/4),
  // W1 max 31*384+383 = 12287 (< 64*768/4), W2 max 31*32+31 = 1023 (< 4096/4).
  const int slice = (b >> 3) & 31;
  v4 pw0 = {0.f, 0.f, 0.f, 0.f}, pw1 = pw0, pw2 = pw0;
  {
    const v4* cw = (const v4*)conv_w;   // 32768 v4
    pw0 = cw[(size_t)slice * 1024 + tid];
    const v4* w1v = (const v4*)W1;      // 12288 v4
    if (tid < 384) pw1 = w1v[(size_t)slice * 384 + tid];
    const v4* w2v = (const v4*)W2;      // 1024 v4
    if (tid < 32) pw2 = w2v[(size_t)slice * 32 + tid];
  }

  // ---- merge the block's 16 waves (flash-style) ----
  if (lane == 0) s_m[wave] = m;
  __syncthreads();
  float m_blk = s_m[0];
#pragma unroll
  for (int i = 1; i < kWaves; ++i) m_blk = fminf(m_blk, s_m[i]);
  const float aw = __expf((m_blk - m) * inv_t1);
  if (lane == 0) s_l[wave] = l * aw;
  ((v4*)&s_cc[wave][0])[lane] = c0 * aw;
  ((v4*)&s_cc[wave][kN])[lane] = c1 * aw;
  __syncthreads();

  // keep prewarm loads alive (rule #17); loads already drained by barrier
  {
    float keep = pw0[0] + pw0[3] + pw1[1] + pw2[2];
    asm volatile("" :: "v"(keep));
  }

  // sum 16 partials; normalize by total l
  const int j = tid & 255, sel = (tid >> 8) & 1;
  float p = 0.f;
  if (tid < 512) {
#pragma unroll
    for (int w = 0; w < kWaves; ++w) p += s_cc[w][sel * kN + j];
  }
  if (tid == 0) {
    float lt = 0.f;
#pragma unroll
    for (int i = 0; i < kWaves; ++i) lt += s_l[i];
    s_invl = 1.0f / lt;
  }
  __syncthreads();
  if (tid < 512) (sel ? s_c1 : s_c0)[j] = p * s_invl;
  __syncthreads();

  // embedding[o] = conv_w[o,:,0].c0 + conv_w[o,:,1].c1 + conv_b[o]
  const v4 cc0 = ((const v4*)s_c0)[lane];
  const v4 cc1 = ((const v4*)s_c1)[lane];
#pragma unroll 4
  for (int o = wave; o < kN; o += kWaves) {
    const v4* wrow = (const v4*)(conv_w + (size_t)o * (2 * kN));
    v4 wa = wrow[2 * lane];       // (i=4l,k=0),(4l,1),(4l+1,0),(4l+1,1)
    v4 wb = wrow[2 * lane + 1];   // (4l+2,0),(4l+2,1),(4l+3,0),(4l+3,1)
    float acc = wa[0] * cc0[0] + wa[1] * cc1[0] + wa[2] * cc0[1] + wa[3] * cc1[1] +
                wb[0] * cc0[2] + wb[1] * cc1[2] + wb[2] * cc0[3] + wb[3] * cc1[3];
    acc = waveReduceSumL63(acc);
    if (lane == 63) s_emb[o] = acc + conv_b[o];
  }
  __syncthreads();

  // h[e] = relu([emb; z] . W1[e,:])
  for (int e = wave; e < kE; e += kWaves) {
    const float* wr = W1 + (size_t)e * (kN + kM);
    float acc = 0.f;
#pragma unroll
    for (int jj = 0; jj < 12; ++jj) {
      int jx = lane + 64 * jj;
      float cj = (jx < kN) ? s_emb[jx] : s_z[jx - kN];
      acc += wr[jx] * cj;
    }
    acc = waveReduceSumL63(acc);
    if (lane == 63) s_h[e] = fmaxf(acc, 0.f);
  }
  __syncthreads();

  // mlp + softmax over experts (wave 0, lane = expert)
  if (wave == 0) {
    const float temp2 = fmaxf(fabsf(t2p[0]), TEMP_MIN_F);
    float acc = 0.f;
    const float* w2r = W2 + (size_t)lane * kE;
#pragma unroll
    for (int e = 0; e < kE; ++e) acc += w2r[e] * s_h[e];
    float logit = -acc / temp2;
    float mx = waveReduceMax(logit);
    float ex = __expf(logit - mx);
    float ssum = waveReduceSum(ex);
    out[(size_t)lane * kB + b] = ex / ssum;
  }
}

extern "C" void kernel_launch(void* const* d_in, const int* in_sizes, int n_in,
                              void* d_out, int out_size, void* d_ws, size_t ws_size,
                              hipStream_t stream) {
  const float* context = (const float*)d_in[0];
  const float* z       = (const float*)d_in[1];
  // d_in[2] = D — structurally [I_N | 0]; D@z == z[:N,:], so unused.
  const float* conv_w  = (const float*)d_in[3];
  const float* conv_b  = (const float*)d_in[4];
  const float* W1      = (const float*)d_in[5];
  const float* W2      = (const float*)d_in[6];
  const float* t1      = (const float*)d_in[7];
  const float* t2      = (const float*)d_in[8];
  float* out = (float*)d_out;
  (void)d_ws; (void)ws_size;  // fully fused: no workspace round-trip

  hipLaunchKernelGGL(k_all, dim3(kB), dim3(1024), 0, stream,
                     context, z, conv_w, conv_b, W1, W2, t1, t2, out);
}